// Round 1
// baseline (2501.223 us; speedup 1.0000x reference)
//
#include <hip/hip_runtime.h>
#include <math.h>

#define GG 32
#define NV (GG * GG * GG)      // 32768 voxels
#define BB 4
#define DD 128

// Monotone order-preserving float->uint encoding (for atomicMax on floats).
__device__ __forceinline__ unsigned int enc_f(float f) {
    unsigned int u = __float_as_uint(f);
    return (u & 0x80000000u) ? ~u : (u | 0x80000000u);
}
__device__ __forceinline__ float dec_f(unsigned int u) {
    return __uint_as_float((u & 0x80000000u) ? (u ^ 0x80000000u) : ~u);
}
// enc(-inf) = ~0xFF800000 = 0x007FFFFF ; enc(+inf) = 0xFF800000
#define ENC_NEG_INF 0x007FFFFFu
#define ENC_POS_INF 0xFF800000u

// ws layout (uint32): [b*6 + 0..2] = enc(min xyz), [b*6 + 3..5] = enc(max xyz)

__global__ void k_init(unsigned int* __restrict__ out_u,
                       unsigned int* __restrict__ ws_u,
                       long nvox, long off_cnt, long ncnt) {
    long i = blockIdx.x * (long)blockDim.x + threadIdx.x;
    long stride = gridDim.x * (long)blockDim.x;
    for (long j = i; j < nvox; j += stride) out_u[j] = ENC_NEG_INF;
    for (long j = i; j < ncnt; j += stride) out_u[off_cnt + j] = 0u;
    if (i < BB * 6) {
        int r = (int)(i % 6);
        ws_u[i] = (r < 3) ? ENC_POS_INF : ENC_NEG_INF;
    }
}

__global__ void k_minmax(const float* __restrict__ xyz,
                         unsigned int* __restrict__ ws_u, int N) {
    int n = blockIdx.x * blockDim.x + threadIdx.x;
    int b = blockIdx.y;
    float mn[3] = {INFINITY, INFINITY, INFINITY};
    float mx[3] = {-INFINITY, -INFINITY, -INFINITY};
    if (n < N) {
        const float* p = xyz + ((size_t)b * N + n) * 3;
        for (int k = 0; k < 3; k++) { float v = p[k]; mn[k] = v; mx[k] = v; }
    }
    // wave-64 butterfly reduce
    for (int o = 32; o > 0; o >>= 1) {
        for (int k = 0; k < 3; k++) {
            mn[k] = fminf(mn[k], __shfl_xor(mn[k], o));
            mx[k] = fmaxf(mx[k], __shfl_xor(mx[k], o));
        }
    }
    if ((threadIdx.x & 63) == 0) {
        for (int k = 0; k < 3; k++) {
            atomicMin(&ws_u[b * 6 + k], enc_f(mn[k]));
            atomicMax(&ws_u[b * 6 + 3 + k], enc_f(mx[k]));
        }
    }
}

__global__ void k_idx(const float* __restrict__ xyz,
                      const unsigned int* __restrict__ ws_u,
                      float* __restrict__ out_idx,
                      int* __restrict__ cnt, int N) {
    int n = blockIdx.x * blockDim.x + threadIdx.x;
    int b = blockIdx.y;
    if (n >= N) return;
    const float CLIP_HI = 1.0f - 1e-6f;
    const float* p = xyz + ((size_t)b * N + n) * 3;
    int vi[3];
    for (int k = 0; k < 3; k++) {
        float mnv = dec_f(ws_u[b * 6 + k]);
        float mxv = dec_f(ws_u[b * 6 + 3 + k]);
        float rng = (mxv - mnv) + 1e-8f;           // matches ref op order
        float t = (p[k] - mnv) / rng;              // IEEE div, matches numpy
        t = fminf(fmaxf(t, 0.0f), CLIP_HI);
        int q = (int)floorf(t * 32.0f);
        q = min(max(q, 0), GG - 1);
        vi[k] = q;
    }
    int idx = vi[0] * (GG * GG) + vi[1] * GG + vi[2];
    out_idx[(size_t)b * N + n] = (float)idx;
    atomicAdd(&cnt[b * NV + idx], 1);
}

__global__ void k_scatter(const float* __restrict__ feat,
                          const float* __restrict__ out_idx,
                          unsigned int* __restrict__ vox, int N) {
    int n = blockIdx.x * blockDim.x + threadIdx.x;
    int b = blockIdx.y;
    if (n >= N) return;
    int idx = (int)out_idx[(size_t)b * N + n];
    const float* fp = feat + (size_t)b * DD * N + n;
    unsigned int* vp = vox + (size_t)b * DD * NV + idx;
    #pragma unroll 4
    for (int d = 0; d < DD; d++) {
        atomicMax(vp + (size_t)d * NV, enc_f(fp[(size_t)d * N]));
    }
}

__global__ void k_fin_vox(unsigned int* __restrict__ out_u,
                          const int* __restrict__ cnt) {
    size_t i = blockIdx.x * (size_t)blockDim.x + threadIdx.x;  // exact: 16777216
    int b = (int)(i >> 22);            // D*V = 2^22
    int v = (int)(i & (NV - 1));
    unsigned int u = out_u[i];
    float f = (cnt[b * NV + v] == 0) ? 0.0f : dec_f(u);
    ((float*)out_u)[i] = f;
}

__global__ void k_fin_tail(float* __restrict__ out,
                           const unsigned int* __restrict__ ws_u,
                           long off_cnt, long off_mm) {
    int i = blockIdx.x * blockDim.x + threadIdx.x;
    if (i < BB * NV) {
        int c = ((const int*)out)[off_cnt + i];
        out[off_cnt + i] = (float)c;
    }
    if (i < BB * 3) {
        int b = i / 3, k = i % 3;
        out[off_mm + i]      = dec_f(ws_u[b * 6 + k]);      // xyz_min [B,3,1]
        out[off_mm + 12 + i] = dec_f(ws_u[b * 6 + 3 + k]);  // xyz_max [B,3,1]
    }
}

extern "C" void kernel_launch(void* const* d_in, const int* in_sizes, int n_in,
                              void* d_out, int out_size, void* d_ws, size_t ws_size,
                              hipStream_t stream) {
    const float* features = (const float*)d_in[0];   // [B, D, N]
    const float* xyz      = (const float*)d_in[1];   // [B, N, 3]
    int N = in_sizes[1] / (BB * 3);                  // 100000

    float* out = (float*)d_out;
    unsigned int* out_u = (unsigned int*)d_out;
    unsigned int* ws_u = (unsigned int*)d_ws;

    const long nvox    = (long)BB * DD * NV;         // 16,777,216
    const long off_idx = nvox;
    const long off_cnt = off_idx + (long)BB * N;     // +400,000
    const long ncnt    = (long)BB * NV;              // 131,072
    const long off_mm  = off_cnt + ncnt;             // min then max (12+12)

    float* out_idx = out + off_idx;
    int*   cnt     = (int*)(out + off_cnt);

    int nb = (N + 255) / 256;

    k_init<<<2048, 256, 0, stream>>>(out_u, ws_u, nvox, off_cnt, ncnt);
    k_minmax<<<dim3(nb, BB), 256, 0, stream>>>(xyz, ws_u, N);
    k_idx<<<dim3(nb, BB), 256, 0, stream>>>(xyz, ws_u, out_idx, cnt, N);
    k_scatter<<<dim3(nb, BB), 256, 0, stream>>>(features, out_idx, out_u, N);
    k_fin_vox<<<(unsigned)(nvox / 256), 256, 0, stream>>>(out_u, cnt);
    k_fin_tail<<<(int)((ncnt + 255) / 256), 256, 0, stream>>>(out, ws_u, off_cnt, off_mm);
}